// Round 1
// 152.163 us; speedup vs baseline: 1.0075x; 1.0075x over previous
//
#include <hip/hip_runtime.h>
#include <hip/hip_fp16.h>
#include <stdint.h>

// deform_conv2d: N=8, C=256, H=W=64, OC=256, 3x3, stride=1, pad=1 -> OH=OW=64
// im2col-fused MFMA GEMM. M=32768 (n,oh,ow), N=256 oc, K=2304 (kd = k*256+c).
// R7: f16 fast path -- xb/w3s stored f16, bilinear combine via v_pk_fma_f16
//     (__hfma2) on 16B corner vectors (no unpack/repack; ~68 -> ~20 VALU per
//     thread-chunk), MFMA switched to 16x16x32_f16 (same fragment layout).
//     Coords entry + dup'd weight half2s + 4 corner base pointers hoisted
//     per-tap (loop = 9 taps x 4 channel-chunks); per-chunk gather offset
//     (cc*128) folds into the load immediate. Preps merged into one kernel.
//     BDMA->Bt staging, preload/2-barrier schedule, XCD swizzle unchanged.

typedef _Float16 half8 __attribute__((ext_vector_type(8)));
typedef float f32x4 __attribute__((ext_vector_type(4)));

__device__ __forceinline__ __half2 h2(uint32_t u) {
  return __builtin_bit_cast(__half2, u);
}
__device__ __forceinline__ uint32_t packh2f(float a, float b) {
  return __builtin_bit_cast(uint32_t, __floats2half2_rn(a, b));
}
__device__ __forceinline__ __half2 duplo(uint32_t u) {
  return __half2half2(__builtin_bit_cast(__half, (unsigned short)(u & 0xffffu)));
}
__device__ __forceinline__ __half2 duphi(uint32_t u) {
  return __half2half2(__builtin_bit_cast(__half, (unsigned short)(u >> 16)));
}

// ---- merged prep: [0,2048) x NCHW fp32 -> NHWC f16
//                   [2048,4352) weights -> swizzled f16 image
//                   [4352,5504) offsets -> packed coords {4 x f16 w, 4 x u16 pix}
__global__ __launch_bounds__(256) void prep_all_kernel(
    const float* __restrict__ x, const float* __restrict__ w,
    const float* __restrict__ offset,
    unsigned short* __restrict__ xb, unsigned short* __restrict__ w3s,
    unsigned short* __restrict__ coords) {
  __shared__ float tile[64][65];
  int tid = threadIdx.x;
  if (blockIdx.x < 2048) {
    int bn   = blockIdx.x >> 8;
    int rem  = blockIdx.x & 255;
    int y    = rem >> 2;
    int cblk = rem & 3;
    const float* src = x + ((size_t)(bn * 256 + cblk * 64)) * 4096 + y * 64;
#pragma unroll
    for (int i = 0; i < 4; ++i) {
      int u  = i * 256 + tid;
      int cl = u >> 4;
      int xs = (u & 15) * 4;
      float4 v = *(const float4*)(src + cl * 4096 + xs);
      tile[cl][xs] = v.x; tile[cl][xs + 1] = v.y;
      tile[cl][xs + 2] = v.z; tile[cl][xs + 3] = v.w;
    }
    __syncthreads();
    unsigned short* dst = xb + ((size_t)(bn * 64 + y) * 64) * 256 + cblk * 64;
#pragma unroll
    for (int i = 0; i < 8; ++i) {
      int v2  = i * 256 + tid;
      int xc  = v2 >> 5;
      int cl2 = (v2 & 31) * 2;
      *(uint32_t*)(dst + xc * 256 + cl2) = packh2f(tile[cl2][xc], tile[cl2 + 1][xc]);
    }
  } else if (blockIdx.x < 4352) {
    int idx = (blockIdx.x - 2048) * 256 + tid;   // < 589824
    int t   = idx >> 14;
    int r2  = idx & 16383;
    int g   = r2 >> 3;
    int e   = r2 & 7;
    int oc  = g >> 3;
    int kk8 = (g & 7) ^ (oc & 7);
    int kk  = kk8 * 8 + e;
    int c   = (t & 3) * 64 + kk;
    int k   = t >> 2;
    w3s[idx] = __builtin_bit_cast(unsigned short, __float2half(w[(oc * 256 + c) * 9 + k]));
  } else {
    int idx = (blockIdx.x - 4352) * 256 + tid;   // < 294912
    int ow  = idx & 63;
    int oh  = (idx >> 6) & 63;
    int r   = idx >> 12;          // bn*9 + k
    int k   = r % 9;
    int bn  = r / 9;
    int ky = k / 3 - 1;
    int kx = k % 3 - 1;
    float offy = offset[((bn * 18 + 2 * k    ) * 64 + oh) * 64 + ow];
    float offx = offset[((bn * 18 + 2 * k + 1) * 64 + oh) * 64 + ow];
    float y = (float)(oh + ky) + offy;
    float x2 = (float)(ow + kx) + offx;
    float y0f = floorf(y), x0f = floorf(x2);
    float fy = y - y0f, fx = x2 - x0f;
    int y0 = (int)y0f, x0 = (int)x0f;
    int y1 = y0 + 1, x1 = x0 + 1;
    float vy0 = (y0 >= 0 && y0 <= 63) ? 1.0f : 0.0f;
    float vy1 = (y1 >= 0 && y1 <= 63) ? 1.0f : 0.0f;
    float vx0 = (x0 >= 0 && x0 <= 63) ? 1.0f : 0.0f;
    float vx1 = (x1 >= 0 && x1 <= 63) ? 1.0f : 0.0f;
    float wy0 = (1.0f - fy) * vy0, wy1 = fy * vy1;
    float wx0 = (1.0f - fx) * vx0, wx1 = fx * vx1;
    int y0c = min(max(y0, 0), 63), y1c = min(max(y1, 0), 63);
    int x0c = min(max(x0, 0), 63), x1c = min(max(x1, 0), 63);
    unsigned short ent[8];
    ent[0] = __builtin_bit_cast(unsigned short, __float2half(wy0 * wx0));
    ent[1] = __builtin_bit_cast(unsigned short, __float2half(wy0 * wx1));
    ent[2] = __builtin_bit_cast(unsigned short, __float2half(wy1 * wx0));
    ent[3] = __builtin_bit_cast(unsigned short, __float2half(wy1 * wx1));
    ent[4] = (unsigned short)(y0c * 64 + x0c);
    ent[5] = (unsigned short)(y0c * 64 + x1c);
    ent[6] = (unsigned short)(y1c * 64 + x0c);
    ent[7] = (unsigned short)(y1c * 64 + x1c);
    *(uint4*)(coords + (size_t)idx * 8) = *(const uint4*)ent;
  }
}

// ---- main: 512 blocks x 512 threads; block tile 64 rows x 256 oc; wave 32x64 ----
__global__ __launch_bounds__(512, 4) void deform_mfma_kernel(
    const unsigned short* __restrict__ xb,      // NHWC f16
    const unsigned short* __restrict__ coords,  // packed coord entries
    const unsigned short* __restrict__ w3s,     // swizzled chunk-major f16
    float* __restrict__ out) {                  // (8, 256, 64, 64) fp32
  __shared__ __align__(16) unsigned short At[64 * 72];   // 9216 B (single)
  __shared__ __align__(16) unsigned short Bt[256 * 64];  // 32768 B (single, swizzled)

  int bn  = blockIdx.x & 7;      // XCD swizzle
  int oh  = blockIdx.x >> 3;
  int tid = threadIdx.x;

  int w    = tid >> 6;            // wave 0..7
  int lane = tid & 63;
  int wrow = w & 1;               // row half (32 rows)
  int wcol = w >> 1;              // oc quarter (64 oc)
  int mrow = lane & 15;
  int quad = lane >> 4;

  // staging identity: one thread = one (row, 8-ch group) unit
  int srow = tid >> 3;             // 0..63
  int sg   = tid & 7;              // channel group

  const unsigned short* xbn = xb + (size_t)bn * (64 * 64 * 256);
  const char* gbase = (const char*)xbn + sg * 16;            // + pix*512 (+ cc*128)
  const unsigned short* cbase = coords + ((size_t)((bn * 9) * 64 + oh) * 64 + srow) * 8;
  unsigned short* awr = At + srow * 72 + sg * 8;

  f32x4 acc[2][4] = {};

#define BDMA(TT)                                                                \
  {                                                                             \
    const unsigned short* src = w3s + (TT) * 16384;                             \
    _Pragma("unroll")                                                           \
    for (int j = 0; j < 4; ++j) {                                               \
      int base16 = j * 512 + w * 64;                                            \
      __builtin_amdgcn_global_load_lds(                                         \
          (const __attribute__((address_space(1))) void*)(src + (base16 + lane) * 8), \
          (__attribute__((address_space(3))) void*)(Bt + base16 * 8),           \
          16, 0, 0);                                                            \
    }                                                                           \
  }

  // one 16B bilinear-sample unit per thread, packed-f16 math.
  // p00..p11 / w00..w11 are per-tap loop-carried; (TT)&3 folds into the
  // load immediate offset (compile-time within the unrolled cc loop).
#define ASTAGE(TT)                                                              \
  {                                                                             \
    uint4 c00 = *(const uint4*)(p00 + ((TT) & 3) * 128);                        \
    uint4 c01 = *(const uint4*)(p01 + ((TT) & 3) * 128);                        \
    uint4 c10 = *(const uint4*)(p10 + ((TT) & 3) * 128);                        \
    uint4 c11 = *(const uint4*)(p11 + ((TT) & 3) * 128);                        \
    __half2 r0 = __hmul2(h2(c00.x), w00);                                       \
    r0 = __hfma2(h2(c01.x), w01, r0);                                           \
    r0 = __hfma2(h2(c10.x), w10, r0);                                           \
    r0 = __hfma2(h2(c11.x), w11, r0);                                           \
    __half2 r1 = __hmul2(h2(c00.y), w00);                                       \
    r1 = __hfma2(h2(c01.y), w01, r1);                                           \
    r1 = __hfma2(h2(c10.y), w10, r1);                                           \
    r1 = __hfma2(h2(c11.y), w11, r1);                                           \
    __half2 r2 = __hmul2(h2(c00.z), w00);                                       \
    r2 = __hfma2(h2(c01.z), w01, r2);                                           \
    r2 = __hfma2(h2(c10.z), w10, r2);                                           \
    r2 = __hfma2(h2(c11.z), w11, r2);                                           \
    __half2 r3 = __hmul2(h2(c00.w), w00);                                       \
    r3 = __hfma2(h2(c01.w), w01, r3);                                           \
    r3 = __hfma2(h2(c10.w), w10, r3);                                           \
    r3 = __hfma2(h2(c11.w), w11, r3);                                           \
    uint4 pk;                                                                   \
    pk.x = __builtin_bit_cast(uint32_t, r0);                                    \
    pk.y = __builtin_bit_cast(uint32_t, r1);                                    \
    pk.z = __builtin_bit_cast(uint32_t, r2);                                    \
    pk.w = __builtin_bit_cast(uint32_t, r3);                                    \
    *(uint4*)awr = pk;                                                          \
  }

#define TAPSETUP(TAP)                                                           \
  {                                                                             \
    uint4 ce = *(const uint4*)(cbase + (TAP) * 32768);                          \
    w00 = duplo(ce.x); w01 = duphi(ce.x);                                       \
    w10 = duplo(ce.y); w11 = duphi(ce.y);                                       \
    p00 = gbase + ((size_t)(ce.z & 0xffffu) << 9);                              \
    p01 = gbase + ((size_t)(ce.z >> 16) << 9);                                  \
    p10 = gbase + ((size_t)(ce.w & 0xffffu) << 9);                              \
    p11 = gbase + ((size_t)(ce.w >> 16) << 9);                                  \
  }

  __half2 w00, w01, w10, w11;
  const char *p00, *p01, *p10, *p11;

  // prologue: stage chunk 0 (tap 0)
  TAPSETUP(0)
  BDMA(0)
  ASTAGE(0)
  __syncthreads();

  half8 af[2][2];
  half8 bfr[2][4];

  for (int tap = 0; tap < 9; ++tap) {
#pragma unroll
    for (int cc = 0; cc < 4; ++cc) {
      const int t = tap * 4 + cc;
      // ---- preload all fragments for chunk t into registers ----
#pragma unroll
      for (int ks = 0; ks < 2; ++ks) {
#pragma unroll
        for (int m = 0; m < 2; ++m)
          af[m][ks] = *(const half8*)(&At[(wrow * 32 + m * 16 + mrow) * 72 + ks * 32 + quad * 8]);
#pragma unroll
        for (int nn = 0; nn < 4; ++nn) {
          int oc  = wcol * 64 + nn * 16 + mrow;
          int g16 = oc * 8 + ((ks * 4 + quad) ^ (mrow & 7));
          bfr[ks][nn] = *(const half8*)(&Bt[g16 * 8]);
        }
      }
      __syncthreads();   // all waves done reading At/Bt -> safe to overwrite

      // ---- stage chunk t+1 (global->LDS) while MFMA(t) runs from registers ----
      if (t < 35) {
        BDMA(t + 1)
        if (cc == 3) TAPSETUP(tap + 1)   // next tap's coords/weights/pointers
        ASTAGE(t + 1)
      }
#pragma unroll
      for (int ks = 0; ks < 2; ++ks)
#pragma unroll
        for (int m = 0; m < 2; ++m)
#pragma unroll
          for (int nn = 0; nn < 4; ++nn)
            acc[m][nn] = __builtin_amdgcn_mfma_f32_16x16x32_f16(af[m][ks], bfr[ks][nn], acc[m][nn], 0, 0, 0);
      __syncthreads();   // staging complete before next preload
    }
  }

  // ---- epilogue: C/D layout col=lane&15(oc), row=quad*4+reg(ow) ----
  float* outp = out + (size_t)(bn * 256) * 4096 + oh * 64;
#pragma unroll
  for (int m = 0; m < 2; ++m) {
    int ow0 = wrow * 32 + m * 16 + quad * 4;
#pragma unroll
    for (int nn = 0; nn < 4; ++nn) {
      int oc = wcol * 64 + nn * 16 + mrow;
      *(f32x4*)(outp + oc * 4096 + ow0) = acc[m][nn];
    }
  }
#undef BDMA
#undef ASTAGE
#undef TAPSETUP
}

extern "C" void kernel_launch(void* const* d_in, const int* in_sizes, int n_in,
                              void* d_out, int out_size, void* d_ws, size_t ws_size,
                              hipStream_t stream) {
  (void)in_sizes; (void)n_in; (void)out_size; (void)ws_size;
  const float* x      = (const float*)d_in[0];
  const float* offset = (const float*)d_in[1];
  const float* weight = (const float*)d_in[2];
  float* out = (float*)d_out;

  unsigned short* xb     = (unsigned short*)d_ws;                        // 16.78 MB
  unsigned short* w3s    = xb + (size_t)8 * 64 * 64 * 256;               // +1.18 MB
  unsigned short* coords = w3s + (size_t)36 * 16384;                     // +4.72 MB

  prep_all_kernel<<<5504, 256, 0, stream>>>(x, weight, offset, xb, w3s, coords);
  deform_mfma_kernel<<<512, 512, 0, stream>>>(xb, coords, w3s, out);
}

// Round 2
// 147.126 us; speedup vs baseline: 1.0420x; 1.0342x over previous
//
#include <hip/hip_runtime.h>
#include <hip/hip_fp16.h>
#include <stdint.h>

// deform_conv2d: N=8, C=256, H=W=64, OC=256, 3x3, stride=1, pad=1 -> OH=OW=64
// im2col-fused MFMA GEMM. M=32768 (n,oh,ow), N=256 oc, K=2304 (kd = k*256+c).
// R8: de-serialize the chunk loop. Double-buffered At/Bt + ONE barrier per
//     chunk: stage(t+1)->buf[1-p] issues in the same region as preload(t)+
//     MFMA(t) from buf[p], so LDS-read / gather / f16-math / MFMA phases of
//     all 8 waves overlap instead of lockstepping (R7 showed all pipes ~25%:
//     wall = SUM of pipes -> barrier-serialized). At pad-72 replaced by XOR
//     group swizzle (row&7) so 2x(At 8K + Bt 32K) = 81920 B/block -> exactly
//     2 blocks/CU at 160 KiB. Coords for next tap prefetched to a register
//     at cc==2. Buffer parity p = cc&1 is compile-time (unrolled cc loop).

typedef _Float16 half8 __attribute__((ext_vector_type(8)));
typedef float f32x4 __attribute__((ext_vector_type(4)));

__device__ __forceinline__ __half2 h2(uint32_t u) {
  return __builtin_bit_cast(__half2, u);
}
__device__ __forceinline__ uint32_t packh2f(float a, float b) {
  return __builtin_bit_cast(uint32_t, __floats2half2_rn(a, b));
}
__device__ __forceinline__ __half2 duplo(uint32_t u) {
  return __half2half2(__builtin_bit_cast(__half, (unsigned short)(u & 0xffffu)));
}
__device__ __forceinline__ __half2 duphi(uint32_t u) {
  return __half2half2(__builtin_bit_cast(__half, (unsigned short)(u >> 16)));
}

// ---- merged prep: [0,2048) x NCHW fp32 -> NHWC f16
//                   [2048,4352) weights -> swizzled f16 image
//                   [4352,5504) offsets -> packed coords {4 x f16 w, 4 x u16 pix}
__global__ __launch_bounds__(256) void prep_all_kernel(
    const float* __restrict__ x, const float* __restrict__ w,
    const float* __restrict__ offset,
    unsigned short* __restrict__ xb, unsigned short* __restrict__ w3s,
    unsigned short* __restrict__ coords) {
  __shared__ float tile[64][65];
  int tid = threadIdx.x;
  if (blockIdx.x < 2048) {
    int bn   = blockIdx.x >> 8;
    int rem  = blockIdx.x & 255;
    int y    = rem >> 2;
    int cblk = rem & 3;
    const float* src = x + ((size_t)(bn * 256 + cblk * 64)) * 4096 + y * 64;
#pragma unroll
    for (int i = 0; i < 4; ++i) {
      int u  = i * 256 + tid;
      int cl = u >> 4;
      int xs = (u & 15) * 4;
      float4 v = *(const float4*)(src + cl * 4096 + xs);
      tile[cl][xs] = v.x; tile[cl][xs + 1] = v.y;
      tile[cl][xs + 2] = v.z; tile[cl][xs + 3] = v.w;
    }
    __syncthreads();
    unsigned short* dst = xb + ((size_t)(bn * 64 + y) * 64) * 256 + cblk * 64;
#pragma unroll
    for (int i = 0; i < 8; ++i) {
      int v2  = i * 256 + tid;
      int xc  = v2 >> 5;
      int cl2 = (v2 & 31) * 2;
      *(uint32_t*)(dst + xc * 256 + cl2) = packh2f(tile[cl2][xc], tile[cl2 + 1][xc]);
    }
  } else if (blockIdx.x < 4352) {
    int idx = (blockIdx.x - 2048) * 256 + tid;   // < 589824
    int t   = idx >> 14;
    int r2  = idx & 16383;
    int g   = r2 >> 3;
    int e   = r2 & 7;
    int oc  = g >> 3;
    int kk8 = (g & 7) ^ (oc & 7);
    int kk  = kk8 * 8 + e;
    int c   = (t & 3) * 64 + kk;
    int k   = t >> 2;
    w3s[idx] = __builtin_bit_cast(unsigned short, __float2half(w[(oc * 256 + c) * 9 + k]));
  } else {
    int idx = (blockIdx.x - 4352) * 256 + tid;   // < 294912
    int ow  = idx & 63;
    int oh  = (idx >> 6) & 63;
    int r   = idx >> 12;          // bn*9 + k
    int k   = r % 9;
    int bn  = r / 9;
    int ky = k / 3 - 1;
    int kx = k % 3 - 1;
    float offy = offset[((bn * 18 + 2 * k    ) * 64 + oh) * 64 + ow];
    float offx = offset[((bn * 18 + 2 * k + 1) * 64 + oh) * 64 + ow];
    float y = (float)(oh + ky) + offy;
    float x2 = (float)(ow + kx) + offx;
    float y0f = floorf(y), x0f = floorf(x2);
    float fy = y - y0f, fx = x2 - x0f;
    int y0 = (int)y0f, x0 = (int)x0f;
    int y1 = y0 + 1, x1 = x0 + 1;
    float vy0 = (y0 >= 0 && y0 <= 63) ? 1.0f : 0.0f;
    float vy1 = (y1 >= 0 && y1 <= 63) ? 1.0f : 0.0f;
    float vx0 = (x0 >= 0 && x0 <= 63) ? 1.0f : 0.0f;
    float vx1 = (x1 >= 0 && x1 <= 63) ? 1.0f : 0.0f;
    float wy0 = (1.0f - fy) * vy0, wy1 = fy * vy1;
    float wx0 = (1.0f - fx) * vx0, wx1 = fx * vx1;
    int y0c = min(max(y0, 0), 63), y1c = min(max(y1, 0), 63);
    int x0c = min(max(x0, 0), 63), x1c = min(max(x1, 0), 63);
    unsigned short ent[8];
    ent[0] = __builtin_bit_cast(unsigned short, __float2half(wy0 * wx0));
    ent[1] = __builtin_bit_cast(unsigned short, __float2half(wy0 * wx1));
    ent[2] = __builtin_bit_cast(unsigned short, __float2half(wy1 * wx0));
    ent[3] = __builtin_bit_cast(unsigned short, __float2half(wy1 * wx1));
    ent[4] = (unsigned short)(y0c * 64 + x0c);
    ent[5] = (unsigned short)(y0c * 64 + x1c);
    ent[6] = (unsigned short)(y1c * 64 + x0c);
    ent[7] = (unsigned short)(y1c * 64 + x1c);
    *(uint4*)(coords + (size_t)idx * 8) = *(const uint4*)ent;
  }
}

// ---- main: 512 blocks x 512 threads; block tile 64 rows x 256 oc; wave 32x64 ----
__global__ __launch_bounds__(512, 4) void deform_mfma_kernel(
    const unsigned short* __restrict__ xb,      // NHWC f16
    const unsigned short* __restrict__ coords,  // packed coord entries
    const unsigned short* __restrict__ w3s,     // swizzled chunk-major f16
    float* __restrict__ out) {                  // (8, 256, 64, 64) fp32
  // double-buffered; At XOR-swizzled (group ^= row&7), no pad.
  // 2*(8192 + 32768) = 81920 B -> exactly 2 blocks/CU at 160 KiB.
  __shared__ __align__(16) unsigned short At[2][64 * 64];
  __shared__ __align__(16) unsigned short Bt[2][256 * 64];

  int bn  = blockIdx.x & 7;      // XCD swizzle
  int oh  = blockIdx.x >> 3;
  int tid = threadIdx.x;

  int w    = tid >> 6;            // wave 0..7
  int lane = tid & 63;
  int wrow = w & 1;               // row half (32 rows)
  int wcol = w >> 1;              // oc quarter (64 oc)
  int mrow = lane & 15;
  int quad = lane >> 4;

  // staging identity: one thread = one (row, 8-ch group) unit
  int srow = tid >> 3;             // 0..63
  int sg   = tid & 7;              // channel group

  const unsigned short* xbn = xb + (size_t)bn * (64 * 64 * 256);
  const char* gbase = (const char*)xbn + sg * 16;            // + pix*512 (+ cc*128)
  const unsigned short* cbase = coords + ((size_t)((bn * 9) * 64 + oh) * 64 + srow) * 8;
  int aw_off = srow * 64 + ((sg ^ (srow & 7)) * 8);          // XOR-swizzled slot
  unsigned short* awr0 = &At[0][0] + aw_off;
  unsigned short* awr1 = &At[1][0] + aw_off;

  f32x4 acc[2][4] = {};

#define BDMA(TT, BB)                                                            \
  {                                                                             \
    const unsigned short* src = w3s + (TT) * 16384;                             \
    _Pragma("unroll")                                                           \
    for (int j = 0; j < 4; ++j) {                                               \
      int base16 = j * 512 + w * 64;                                            \
      __builtin_amdgcn_global_load_lds(                                         \
          (const __attribute__((address_space(1))) void*)(src + (base16 + lane) * 8), \
          (__attribute__((address_space(3))) void*)(&Bt[BB][0] + base16 * 8),   \
          16, 0, 0);                                                            \
    }                                                                           \
  }

  // one 16B bilinear-sample unit per thread, packed-f16 math.
#define ASTAGE(TT, AW)                                                          \
  {                                                                             \
    uint4 c00 = *(const uint4*)(p00 + ((TT) & 3) * 128);                        \
    uint4 c01 = *(const uint4*)(p01 + ((TT) & 3) * 128);                        \
    uint4 c10 = *(const uint4*)(p10 + ((TT) & 3) * 128);                        \
    uint4 c11 = *(const uint4*)(p11 + ((TT) & 3) * 128);                        \
    __half2 r0 = __hmul2(h2(c00.x), w00);                                       \
    r0 = __hfma2(h2(c01.x), w01, r0);                                           \
    r0 = __hfma2(h2(c10.x), w10, r0);                                           \
    r0 = __hfma2(h2(c11.x), w11, r0);                                           \
    __half2 r1 = __hmul2(h2(c00.y), w00);                                       \
    r1 = __hfma2(h2(c01.y), w01, r1);                                           \
    r1 = __hfma2(h2(c10.y), w10, r1);                                           \
    r1 = __hfma2(h2(c11.y), w11, r1);                                           \
    __half2 r2 = __hmul2(h2(c00.z), w00);                                       \
    r2 = __hfma2(h2(c01.z), w01, r2);                                           \
    r2 = __hfma2(h2(c10.z), w10, r2);                                           \
    r2 = __hfma2(h2(c11.z), w11, r2);                                           \
    __half2 r3 = __hmul2(h2(c00.w), w00);                                       \
    r3 = __hfma2(h2(c01.w), w01, r3);                                           \
    r3 = __hfma2(h2(c10.w), w10, r3);                                           \
    r3 = __hfma2(h2(c11.w), w11, r3);                                           \
    uint4 pk;                                                                   \
    pk.x = __builtin_bit_cast(uint32_t, r0);                                    \
    pk.y = __builtin_bit_cast(uint32_t, r1);                                    \
    pk.z = __builtin_bit_cast(uint32_t, r2);                                    \
    pk.w = __builtin_bit_cast(uint32_t, r3);                                    \
    *(uint4*)(AW) = pk;                                                         \
  }

#define TAPSETUP_R(CE)                                                          \
  {                                                                             \
    w00 = duplo((CE).x); w01 = duphi((CE).x);                                   \
    w10 = duplo((CE).y); w11 = duphi((CE).y);                                   \
    p00 = gbase + ((size_t)((CE).z & 0xffffu) << 9);                            \
    p01 = gbase + ((size_t)((CE).z >> 16) << 9);                                \
    p10 = gbase + ((size_t)((CE).w & 0xffffu) << 9);                            \
    p11 = gbase + ((size_t)((CE).w >> 16) << 9);                                \
  }

  __half2 w00, w01, w10, w11;
  const char *p00, *p01, *p10, *p11;
  uint4 cnext;

  // prologue: tap 0 setup + stage chunk 0 into buffer 0
  {
    uint4 ce0 = *(const uint4*)(cbase);
    TAPSETUP_R(ce0)
  }
  BDMA(0, 0)
  ASTAGE(0, awr0)
  __syncthreads();

  half8 af[2][2];
  half8 bfr[2][4];

  for (int tap = 0; tap < 9; ++tap) {
#pragma unroll
    for (int cc = 0; cc < 4; ++cc) {
      const int t  = tap * 4 + cc;
      const int pb = cc & 1;         // compute buffer (tap*4 is even)

      // ---- stage chunk t+1 into buffer 1-pb (issues early; latency hidden
      //      under this chunk's ds_reads + MFMAs; drained at the barrier) ----
      if (t < 35) {
        BDMA(t + 1, 1 - pb)
        if (cc == 2 && tap < 8) cnext = *(const uint4*)(cbase + (tap + 1) * 32768);
        if (cc == 3) TAPSETUP_R(cnext)       // VALU-only (coords prefetched)
        ASTAGE(t + 1, pb ? awr0 : awr1)
      }

      // ---- preload all fragments for chunk t from buffer pb ----
      {
        const unsigned short* Atp = &At[pb][0];
        const unsigned short* Btp = &Bt[pb][0];
#pragma unroll
        for (int ks = 0; ks < 2; ++ks) {
#pragma unroll
          for (int m = 0; m < 2; ++m) {
            int R = wrow * 32 + m * 16 + mrow;
            af[m][ks] = *(const half8*)(Atp + R * 64 + (((ks * 4 + quad) ^ (mrow & 7)) * 8));
          }
#pragma unroll
          for (int nn = 0; nn < 4; ++nn) {
            int oc  = wcol * 64 + nn * 16 + mrow;
            int g16 = oc * 8 + ((ks * 4 + quad) ^ (mrow & 7));
            bfr[ks][nn] = *(const half8*)(Btp + g16 * 8);
          }
        }
      }

#pragma unroll
      for (int ks = 0; ks < 2; ++ks)
#pragma unroll
        for (int m = 0; m < 2; ++m)
#pragma unroll
          for (int nn = 0; nn < 4; ++nn)
            acc[m][nn] = __builtin_amdgcn_mfma_f32_16x16x32_f16(af[m][ks], bfr[ks][nn], acc[m][nn], 0, 0, 0);

      __syncthreads();   // staged buffer 1-pb complete; buffer pb free to overwrite
    }
  }

  // ---- epilogue: C/D layout col=lane&15(oc), row=quad*4+reg(ow) ----
  float* outp = out + (size_t)(bn * 256) * 4096 + oh * 64;
#pragma unroll
  for (int m = 0; m < 2; ++m) {
    int ow0 = wrow * 32 + m * 16 + quad * 4;
#pragma unroll
    for (int nn = 0; nn < 4; ++nn) {
      int oc = wcol * 64 + nn * 16 + mrow;
      *(f32x4*)(outp + oc * 4096 + ow0) = acc[m][nn];
    }
  }
#undef BDMA
#undef ASTAGE
#undef TAPSETUP_R
}

extern "C" void kernel_launch(void* const* d_in, const int* in_sizes, int n_in,
                              void* d_out, int out_size, void* d_ws, size_t ws_size,
                              hipStream_t stream) {
  (void)in_sizes; (void)n_in; (void)out_size; (void)ws_size;
  const float* x      = (const float*)d_in[0];
  const float* offset = (const float*)d_in[1];
  const float* weight = (const float*)d_in[2];
  float* out = (float*)d_out;

  unsigned short* xb     = (unsigned short*)d_ws;                        // 16.78 MB
  unsigned short* w3s    = xb + (size_t)8 * 64 * 64 * 256;               // +1.18 MB
  unsigned short* coords = w3s + (size_t)36 * 16384;                     // +4.72 MB

  prep_all_kernel<<<5504, 256, 0, stream>>>(x, weight, offset, xb, w3s, coords);
  deform_mfma_kernel<<<512, 512, 0, stream>>>(xb, coords, w3s, out);
}

// Round 3
// 144.781 us; speedup vs baseline: 1.0589x; 1.0162x over previous
//
#include <hip/hip_runtime.h>
#include <hip/hip_fp16.h>
#include <stdint.h>

// deform_conv2d: N=8, C=256, H=W=64, OC=256, 3x3, stride=1, pad=1 -> OH=OW=64
// im2col-fused MFMA GEMM. M=32768 (n,oh,ow), N=256 oc, K=2304 (kd = k*256+c).
// R9: LDS-traffic cut (R8 PMC: LDS pipe ~60-66% = top consumer; MFMA 29%).
//  (a) B bypasses LDS entirely: w3s is already fragment-ordered, so each wave
//      loads its 8 B-frags/chunk straight into registers (double-buffered reg
//      sets bA/bB; the per-chunk __syncthreads vmcnt(0) drain guarantees
//      completion before use next chunk). Deletes 8/12 ds_reads per wave and
//      all BDMA LDS writes.
//  (b) 2x M-tile: 256 blocks (exactly 1/CU), tile 128 rows x 256 oc, 8 waves
//      of 64x64 (acc[4][4]) -> A-frag LDS bytes per output halve.
//  LDS now At only: 2 x 16 KB = 32 KB. XOR group swizzle kept (0 conflicts).
//  Each thread stages 2 bilinear units/chunk (rows srow and srow+64 = the
//  block's two oh rows). 1 barrier per chunk.

typedef _Float16 half8 __attribute__((ext_vector_type(8)));
typedef float f32x4 __attribute__((ext_vector_type(4)));

__device__ __forceinline__ __half2 h2(uint32_t u) {
  return __builtin_bit_cast(__half2, u);
}
__device__ __forceinline__ uint32_t packh2f(float a, float b) {
  return __builtin_bit_cast(uint32_t, __floats2half2_rn(a, b));
}
__device__ __forceinline__ __half2 duplo(uint32_t u) {
  return __half2half2(__builtin_bit_cast(__half, (unsigned short)(u & 0xffffu)));
}
__device__ __forceinline__ __half2 duphi(uint32_t u) {
  return __half2half2(__builtin_bit_cast(__half, (unsigned short)(u >> 16)));
}

// ---- merged prep: [0,2048) x NCHW fp32 -> NHWC f16
//                   [2048,4352) weights -> swizzled f16 image
//                   [4352,5504) offsets -> packed coords {4 x f16 w, 4 x u16 pix}
__global__ __launch_bounds__(256) void prep_all_kernel(
    const float* __restrict__ x, const float* __restrict__ w,
    const float* __restrict__ offset,
    unsigned short* __restrict__ xb, unsigned short* __restrict__ w3s,
    unsigned short* __restrict__ coords) {
  __shared__ float tile[64][65];
  int tid = threadIdx.x;
  if (blockIdx.x < 2048) {
    int bn   = blockIdx.x >> 8;
    int rem  = blockIdx.x & 255;
    int y    = rem >> 2;
    int cblk = rem & 3;
    const float* src = x + ((size_t)(bn * 256 + cblk * 64)) * 4096 + y * 64;
#pragma unroll
    for (int i = 0; i < 4; ++i) {
      int u  = i * 256 + tid;
      int cl = u >> 4;
      int xs = (u & 15) * 4;
      float4 v = *(const float4*)(src + cl * 4096 + xs);
      tile[cl][xs] = v.x; tile[cl][xs + 1] = v.y;
      tile[cl][xs + 2] = v.z; tile[cl][xs + 3] = v.w;
    }
    __syncthreads();
    unsigned short* dst = xb + ((size_t)(bn * 64 + y) * 64) * 256 + cblk * 64;
#pragma unroll
    for (int i = 0; i < 8; ++i) {
      int v2  = i * 256 + tid;
      int xc  = v2 >> 5;
      int cl2 = (v2 & 31) * 2;
      *(uint32_t*)(dst + xc * 256 + cl2) = packh2f(tile[cl2][xc], tile[cl2 + 1][xc]);
    }
  } else if (blockIdx.x < 4352) {
    int idx = (blockIdx.x - 2048) * 256 + tid;   // < 589824
    int t   = idx >> 14;
    int r2  = idx & 16383;
    int g   = r2 >> 3;
    int e   = r2 & 7;
    int oc  = g >> 3;
    int kk8 = (g & 7) ^ (oc & 7);
    int kk  = kk8 * 8 + e;
    int c   = (t & 3) * 64 + kk;
    int k   = t >> 2;
    w3s[idx] = __builtin_bit_cast(unsigned short, __float2half(w[(oc * 256 + c) * 9 + k]));
  } else {
    int idx = (blockIdx.x - 4352) * 256 + tid;   // < 294912
    int ow  = idx & 63;
    int oh  = (idx >> 6) & 63;
    int r   = idx >> 12;          // bn*9 + k
    int k   = r % 9;
    int bn  = r / 9;
    int ky = k / 3 - 1;
    int kx = k % 3 - 1;
    float offy = offset[((bn * 18 + 2 * k    ) * 64 + oh) * 64 + ow];
    float offx = offset[((bn * 18 + 2 * k + 1) * 64 + oh) * 64 + ow];
    float y = (float)(oh + ky) + offy;
    float x2 = (float)(ow + kx) + offx;
    float y0f = floorf(y), x0f = floorf(x2);
    float fy = y - y0f, fx = x2 - x0f;
    int y0 = (int)y0f, x0 = (int)x0f;
    int y1 = y0 + 1, x1 = x0 + 1;
    float vy0 = (y0 >= 0 && y0 <= 63) ? 1.0f : 0.0f;
    float vy1 = (y1 >= 0 && y1 <= 63) ? 1.0f : 0.0f;
    float vx0 = (x0 >= 0 && x0 <= 63) ? 1.0f : 0.0f;
    float vx1 = (x1 >= 0 && x1 <= 63) ? 1.0f : 0.0f;
    float wy0 = (1.0f - fy) * vy0, wy1 = fy * vy1;
    float wx0 = (1.0f - fx) * vx0, wx1 = fx * vx1;
    int y0c = min(max(y0, 0), 63), y1c = min(max(y1, 0), 63);
    int x0c = min(max(x0, 0), 63), x1c = min(max(x1, 0), 63);
    unsigned short ent[8];
    ent[0] = __builtin_bit_cast(unsigned short, __float2half(wy0 * wx0));
    ent[1] = __builtin_bit_cast(unsigned short, __float2half(wy0 * wx1));
    ent[2] = __builtin_bit_cast(unsigned short, __float2half(wy1 * wx0));
    ent[3] = __builtin_bit_cast(unsigned short, __float2half(wy1 * wx1));
    ent[4] = (unsigned short)(y0c * 64 + x0c);
    ent[5] = (unsigned short)(y0c * 64 + x1c);
    ent[6] = (unsigned short)(y1c * 64 + x0c);
    ent[7] = (unsigned short)(y1c * 64 + x1c);
    *(uint4*)(coords + (size_t)idx * 8) = *(const uint4*)ent;
  }
}

// ---- main: 256 blocks x 512 threads; block tile 128 rows x 256 oc; wave 64x64 ----
__global__ __launch_bounds__(512, 2) void deform_mfma_kernel(
    const unsigned short* __restrict__ xb,      // NHWC f16
    const unsigned short* __restrict__ coords,  // packed coord entries
    const unsigned short* __restrict__ w3s,     // swizzled chunk-major f16
    float* __restrict__ out) {                  // (8, 256, 64, 64) fp32
  // A-tile only; double-buffered, XOR group swizzle (no pad). 32 KB total.
  __shared__ __align__(16) unsigned short At[2][128 * 64];

  int bn  = blockIdx.x & 7;      // XCD swizzle
  int ohp = blockIdx.x >> 3;     // 0..31 -> oh rows {2*ohp, 2*ohp+1}
  int tid = threadIdx.x;

  int w    = tid >> 6;            // wave 0..7
  int lane = tid & 63;
  int wrow = w & 1;               // 64-row half
  int wcol = w >> 1;              // 64-oc quarter
  int mrow = lane & 15;
  int quad = lane >> 4;

  // staging identity: thread = rows {srow, srow+64} x channel-group sg
  int srow = tid >> 3;             // 0..63
  int sg   = tid & 7;

  const char* xbc = (const char*)(xb + (size_t)bn * (64 * 64 * 256));
  const unsigned short* cb0 = coords + ((size_t)((bn * 9) * 64 + ohp * 2) * 64 + srow) * 8;
  const unsigned short* cb1 = cb0 + 512;   // next oh row

  int aw0 = srow * 64 + ((sg ^ (srow & 7)) * 8);   // shorts; unit2 at +4096
  int grp0 = quad ^ (mrow & 7);
  int grp1 = (4 + quad) ^ (mrow & 7);
  int a_off0 = (wrow * 64 + mrow) * 64 + grp0 * 8; // shorts; +m*1024
  int a_off1 = (wrow * 64 + mrow) * 64 + grp1 * 8;
  int boff0 = ((wcol * 64 + mrow) * 8 + grp0) * 16; // bytes into w3s chunk
  int boff1 = ((wcol * 64 + mrow) * 8 + grp1) * 16;

  f32x4 acc[4][4] = {};
  half8 bA[2][4], bB[2][4];

  __half2 w00, w01, w02, w03, w10, w11, w12, w13;
  uint32_t o00, o01, o02, o03, o10, o11, o12, o13;
  uint4 cn0, cn1;

  // B frags straight from w3s (fragment-ordered by prep; L2-resident)
#define BLOADR(TT, BS)                                                          \
  {                                                                             \
    const char* wp = (const char*)w3s + (size_t)(TT) * 32768;                   \
    _Pragma("unroll")                                                           \
    for (int nn = 0; nn < 4; ++nn) {                                            \
      BS[0][nn] = *(const half8*)(wp + boff0 + nn * 2048);                      \
      BS[1][nn] = *(const half8*)(wp + boff1 + nn * 2048);                      \
    }                                                                           \
  }

#define TAPSETUP_R(CE0, CE1)                                                    \
  {                                                                             \
    w00 = duplo((CE0).x); w01 = duphi((CE0).x);                                 \
    w02 = duplo((CE0).y); w03 = duphi((CE0).y);                                 \
    o00 = (((CE0).z & 0xffffu) << 9) + sg * 16;                                 \
    o01 = (((CE0).z >> 16) << 9) + sg * 16;                                     \
    o02 = (((CE0).w & 0xffffu) << 9) + sg * 16;                                 \
    o03 = (((CE0).w >> 16) << 9) + sg * 16;                                     \
    w10 = duplo((CE1).x); w11 = duphi((CE1).x);                                 \
    w12 = duplo((CE1).y); w13 = duphi((CE1).y);                                 \
    o10 = (((CE1).z & 0xffffu) << 9) + sg * 16;                                 \
    o11 = (((CE1).z >> 16) << 9) + sg * 16;                                     \
    o12 = (((CE1).w & 0xffffu) << 9) + sg * 16;                                 \
    o13 = (((CE1).w >> 16) << 9) + sg * 16;                                     \
  }

  // two 16B bilinear units per thread (rows srow, srow+64), packed-f16 math
#define ASTAGE(TT, ATP)                                                         \
  {                                                                             \
    {                                                                           \
      uint4 c0 = *(const uint4*)(xbc + o00 + ((TT) & 3) * 128);                 \
      uint4 c1 = *(const uint4*)(xbc + o01 + ((TT) & 3) * 128);                 \
      uint4 c2 = *(const uint4*)(xbc + o02 + ((TT) & 3) * 128);                 \
      uint4 c3 = *(const uint4*)(xbc + o03 + ((TT) & 3) * 128);                 \
      __half2 r0 = __hmul2(h2(c0.x), w00);                                      \
      r0 = __hfma2(h2(c1.x), w01, r0); r0 = __hfma2(h2(c2.x), w02, r0);         \
      r0 = __hfma2(h2(c3.x), w03, r0);                                          \
      __half2 r1 = __hmul2(h2(c0.y), w00);                                      \
      r1 = __hfma2(h2(c1.y), w01, r1); r1 = __hfma2(h2(c2.y), w02, r1);         \
      r1 = __hfma2(h2(c3.y), w03, r1);                                          \
      __half2 r2 = __hmul2(h2(c0.z), w00);                                      \
      r2 = __hfma2(h2(c1.z), w01, r2); r2 = __hfma2(h2(c2.z), w02, r2);         \
      r2 = __hfma2(h2(c3.z), w03, r2);                                          \
      __half2 r3 = __hmul2(h2(c0.w), w00);                                      \
      r3 = __hfma2(h2(c1.w), w01, r3); r3 = __hfma2(h2(c2.w), w02, r3);         \
      r3 = __hfma2(h2(c3.w), w03, r3);                                          \
      uint4 pk;                                                                 \
      pk.x = __builtin_bit_cast(uint32_t, r0);                                  \
      pk.y = __builtin_bit_cast(uint32_t, r1);                                  \
      pk.z = __builtin_bit_cast(uint32_t, r2);                                  \
      pk.w = __builtin_bit_cast(uint32_t, r3);                                  \
      *(uint4*)((ATP) + aw0) = pk;                                              \
    }                                                                           \
    {                                                                           \
      uint4 c0 = *(const uint4*)(xbc + o10 + ((TT) & 3) * 128);                 \
      uint4 c1 = *(const uint4*)(xbc + o11 + ((TT) & 3) * 128);                 \
      uint4 c2 = *(const uint4*)(xbc + o12 + ((TT) & 3) * 128);                 \
      uint4 c3 = *(const uint4*)(xbc + o13 + ((TT) & 3) * 128);                 \
      __half2 r0 = __hmul2(h2(c0.x), w10);                                      \
      r0 = __hfma2(h2(c1.x), w11, r0); r0 = __hfma2(h2(c2.x), w12, r0);         \
      r0 = __hfma2(h2(c3.x), w13, r0);                                          \
      __half2 r1 = __hmul2(h2(c0.y), w10);                                      \
      r1 = __hfma2(h2(c1.y), w11, r1); r1 = __hfma2(h2(c2.y), w12, r1);         \
      r1 = __hfma2(h2(c3.y), w13, r1);                                          \
      __half2 r2 = __hmul2(h2(c0.z), w10);                                      \
      r2 = __hfma2(h2(c1.z), w11, r2); r2 = __hfma2(h2(c2.z), w12, r2);         \
      r2 = __hfma2(h2(c3.z), w13, r2);                                          \
      __half2 r3 = __hmul2(h2(c0.w), w10);                                      \
      r3 = __hfma2(h2(c1.w), w11, r3); r3 = __hfma2(h2(c2.w), w12, r3);         \
      r3 = __hfma2(h2(c3.w), w13, r3);                                          \
      uint4 pk;                                                                 \
      pk.x = __builtin_bit_cast(uint32_t, r0);                                  \
      pk.y = __builtin_bit_cast(uint32_t, r1);                                  \
      pk.z = __builtin_bit_cast(uint32_t, r2);                                  \
      pk.w = __builtin_bit_cast(uint32_t, r3);                                  \
      *(uint4*)((ATP) + aw0 + 4096) = pk;                                       \
    }                                                                           \
  }

#define COMPUTE(ATP, BS)                                                        \
  {                                                                             \
    _Pragma("unroll")                                                           \
    for (int m = 0; m < 4; ++m) {                                               \
      half8 af0 = *(const half8*)((ATP) + a_off0 + m * 1024);                   \
      half8 af1 = *(const half8*)((ATP) + a_off1 + m * 1024);                   \
      _Pragma("unroll")                                                         \
      for (int nn = 0; nn < 4; ++nn) {                                          \
        acc[m][nn] = __builtin_amdgcn_mfma_f32_16x16x32_f16(af0, BS[0][nn], acc[m][nn], 0, 0, 0); \
        acc[m][nn] = __builtin_amdgcn_mfma_f32_16x16x32_f16(af1, BS[1][nn], acc[m][nn], 0, 0, 0); \
      }                                                                         \
    }                                                                           \
  }

  // prologue: tap 0 setup + stage chunk 0 (At[0], bA)
  {
    uint4 ce0 = *(const uint4*)cb0;
    uint4 ce1 = *(const uint4*)cb1;
    TAPSETUP_R(ce0, ce1)
  }
  BLOADR(0, bA)
  ASTAGE(0, &At[0][0])
  __syncthreads();

  for (int tap = 0; tap < 9; ++tap) {
#pragma unroll
    for (int cc = 0; cc < 4; ++cc) {
      const int t = tap * 4 + cc;
      // stage chunk t+1 (B -> other reg set, A -> other LDS buffer)
      if (t < 35) {
        if (cc & 1) { BLOADR(t + 1, bA) } else { BLOADR(t + 1, bB) }
        if (cc == 2 && tap < 8) {
          cn0 = *(const uint4*)(cb0 + (tap + 1) * 32768);
          cn1 = *(const uint4*)(cb1 + (tap + 1) * 32768);
        }
        if (cc == 3) TAPSETUP_R(cn0, cn1)
        if (cc & 1) { ASTAGE(t + 1, &At[0][0]) } else { ASTAGE(t + 1, &At[1][0]) }
      }
      // compute chunk t
      if (cc & 1) { COMPUTE(&At[1][0], bB) } else { COMPUTE(&At[0][0], bA) }
      __syncthreads();   // orders At swap; vmcnt(0) drain validates B regs
    }
  }

  // ---- epilogue: C/D layout col=lane&15(oc), row=quad*4+reg(ow) ----
  float* outp = out + (size_t)bn * 256 * 4096 + (size_t)(ohp * 2 + wrow) * 64;
#pragma unroll
  for (int m = 0; m < 4; ++m) {
    int ow0 = m * 16 + quad * 4;
#pragma unroll
    for (int nn = 0; nn < 4; ++nn) {
      int oc = wcol * 64 + nn * 16 + mrow;
      *(f32x4*)(outp + (size_t)oc * 4096 + ow0) = acc[m][nn];
    }
  }
#undef BLOADR
#undef TAPSETUP_R
#undef ASTAGE
#undef COMPUTE
}

extern "C" void kernel_launch(void* const* d_in, const int* in_sizes, int n_in,
                              void* d_out, int out_size, void* d_ws, size_t ws_size,
                              hipStream_t stream) {
  (void)in_sizes; (void)n_in; (void)out_size; (void)ws_size;
  const float* x      = (const float*)d_in[0];
  const float* offset = (const float*)d_in[1];
  const float* weight = (const float*)d_in[2];
  float* out = (float*)d_out;

  unsigned short* xb     = (unsigned short*)d_ws;                        // 16.78 MB
  unsigned short* w3s    = xb + (size_t)8 * 64 * 64 * 256;               // +1.18 MB
  unsigned short* coords = w3s + (size_t)36 * 16384;                     // +4.72 MB

  prep_all_kernel<<<5504, 256, 0, stream>>>(x, weight, offset, xb, w3s, coords);
  deform_mfma_kernel<<<256, 512, 0, stream>>>(xb, coords, w3s, out);
}